// Round 3
// baseline (165.448 us; speedup 1.0000x reference)
//
#include <hip/hip_runtime.h>
#include <hip/hip_bf16.h>

#define FEAT   1024
#define HID    256
#define TSTEPS 24
#define NCLS   10

typedef unsigned int u32;
typedef unsigned long long u64;
typedef unsigned short u16;
typedef float v2f __attribute__((ext_vector_type(2)));

// ---- workspace layout (float offsets). W1T/W2T/W3T carry one extra ZERO row
// (col 1024 / 256) targeted by list padding -> gathers are pure adds.
constexpr int OFF_W1T  = 0;                     // [1025][256] fp32 (W1^T + zero row)
constexpr int OFF_W2T  = OFF_W1T + 1025*HID;    // [257][256]
constexpr int OFF_W3T  = OFF_W2T + 257*HID;     // [257][256]
constexpr int OFF_WLI  = OFF_W3T + 257*HID;     // [10][256] plain copy
constexpr int OFF_B1   = OFF_WLI + NCLS*HID;
constexpr int OFF_B2   = OFF_B1 + HID;
constexpr int OFF_B3   = OFF_B2 + HID;

// ---- LI readout linearized: vo_24 = sum_t coef[t] * (o3_t @ Wli^T).
struct CoefT { float c[TSTEPS]; };
constexpr CoefT make_coef() {
    CoefT r{};
    double c = 0.0, p9 = 1.0;
    r.c[TSTEPS-1] = 0.0f;
    for (int u = TSTEPS-1; u > 0; u--) {
        c = 0.8 * c + 0.1 * p9;
        p9 *= 0.9;
        r.c[u-1] = (float)c;
    }
    return r;
}
__device__ constexpr CoefT COEF = make_coef();

__device__ __forceinline__ u32 rfl(u32 v) {
    return (u32)__builtin_amdgcn_readfirstlane((int)v);   // pin wave-uniform -> SGPR
}

// ---- in-wave dtype detect: fp32 viewed as bf16 -> exponent garbage at even idx.
__device__ __forceinline__ u32 detect_bf16(const void* __restrict__ x, u32 lane) {
    float v = __bfloat162float(((const __hip_bfloat16*)x)[lane]);
    u64 bad = __ballot(!(fabsf(v) < 100.0f));
    return bad == 0ull ? 1u : 0u;
}

__device__ __forceinline__ float rd_any(const void* p, int idx, u32 isbf) {
    return isbf ? __bfloat162float(((const __hip_bfloat16*)p)[idx])
                : ((const float*)p)[idx];
}

__device__ __forceinline__ float4 rd4(const void* p, int i, u32 isbf) {
    if (isbf) {
        const u32* q = (const u32*)p;
        u32 a = q[i >> 1], b = q[(i >> 1) + 1];
        float4 r;
        r.x = __uint_as_float(a << 16); r.y = __uint_as_float(a & 0xffff0000u);
        r.z = __uint_as_float(b << 16); r.w = __uint_as_float(b & 0xffff0000u);
        return r;
    }
    return ((const float4*)p)[i >> 2];
}

// ---- prep: 32x32 LDS-tiled transpose, coalesced float4 both sides, 385 blocks.
__global__ __launch_bounds__(256) void prep_k(const void* __restrict__ x,
        const void* W1, const void* W2, const void* W3, const void* Wli,
        const void* b1, const void* b2, const void* b3, float* __restrict__ ws) {
    const u32 isbf = detect_bf16(x, threadIdx.x & 63);
    const u32 t = threadIdx.x;
    int b = blockIdx.x;

    if (b == 384) {   // tail: Wli + biases + zero rows (all coalesced)
        for (u32 e = t; e < NCLS*HID; e += 256) ws[OFF_WLI + e] = rd_any(Wli, e, isbf);
        ws[OFF_B1 + t] = rd_any(b1, t, isbf);
        ws[OFF_B2 + t] = rd_any(b2, t, isbf);
        ws[OFF_B3 + t] = rd_any(b3, t, isbf);
        ws[OFF_W1T + 1024*HID + t] = 0.f;
        ws[OFF_W2T + 256*HID + t] = 0.f;
        ws[OFF_W3T + 256*HID + t] = 0.f;
        return;
    }

    const void* src; float* dst; int srcW, h0, f0;
    if (b < 256)      { src = W1; dst = ws + OFF_W1T; srcW = FEAT; h0 = (b >> 5) * 32; f0 = (b & 31) * 32; }
    else if (b < 320) { int tb = b - 256; src = W2; dst = ws + OFF_W2T; srcW = HID; h0 = (tb >> 3) * 32; f0 = (tb & 7) * 32; }
    else              { int tb = b - 320; src = W3; dst = ws + OFF_W3T; srcW = HID; h0 = (tb >> 3) * 32; f0 = (tb & 7) * 32; }

    __shared__ float sm[32 * 36];
    {
        u32 r = t >> 3, c4 = (t & 7) * 4;
        float4 w = rd4(src, (h0 + r) * srcW + f0 + c4, isbf);
        *(float4*)&sm[r * 36 + c4] = w;
    }
    __syncthreads();
    {
        u32 f = t >> 3, h4 = (t & 7) * 4;
        float4 o;
        o.x = sm[(h4 + 0) * 36 + f];
        o.y = sm[(h4 + 1) * 36 + f];
        o.z = sm[(h4 + 2) * 36 + f];
        o.w = sm[(h4 + 3) * 36 + f];
        *(float4*)&dst[(size_t)(f0 + f) * HID + h0 + h4] = o;
    }
}

__device__ __forceinline__ u32 mbcnt64(u64 m) {
    return __builtin_amdgcn_mbcnt_hi((u32)(m >> 32),
           __builtin_amdgcn_mbcnt_lo((u32)m, 0u));
}

// ---- list builders: u16 col-index entries; branch-free prefix via weighted
// bit-plane ballots; pad to EVEN count with the zero-row col. Per-WAVE lists. ----

// encoder half: 8 features/lane, col = colbase + 8*lane + j; zero col = 1024.
__device__ __forceinline__ u32 build_listE8(u16* list, u32 lm, u32 lane, u32 colbase) {
    u32 cnt = (u32)__builtin_popcount(lm);          // 0..8
    u32 pos = 0, n = 0;
    #pragma unroll
    for (int b = 0; b < 4; b++) {
        u64 B = __ballot(((cnt >> b) & 1u) != 0);
        pos += mbcnt64(B) << b;
        n += ((u32)__builtin_popcountll(B)) << b;
    }
    while (lm) {
        u32 j = (u32)__builtin_ctz(lm); lm &= lm - 1;
        list[pos++] = (u16)(colbase + (lane << 3) + j);
    }
    u32 np = (n + 1u) & ~1u;
    if (lane == 0 && np != n) list[n] = (u16)1024;
    return np;
}

// z half-layers: 2 neurons/lane, col = 4*lane + kbase + j; zero col = 256;
// append at start (start must be even). returns padded end (even).
__device__ __forceinline__ u32 build_listZ2(u16* list, u32 lm, u32 start, u32 lane, u32 kbase) {
    u32 cnt = (u32)__builtin_popcount(lm);          // 0..2
    u64 B0 = __ballot((cnt & 1u) != 0);
    u64 B1 = __ballot((cnt & 2u) != 0);
    u32 pos = start + mbcnt64(B0) + 2u*mbcnt64(B1);
    u32 n = start + (u32)__builtin_popcountll(B0) + 2u*(u32)__builtin_popcountll(B1);
    while (lm) {
        u32 j = (u32)__builtin_ctz(lm); lm &= lm - 1;
        list[pos++] = (u16)((lane << 2) + kbase + j);
    }
    u32 np = (n + 1u) & ~1u;
    if (lane == 0 && np != n) list[n] = (u16)256;
    return np;
}

#define GADD(AA, BB, V) do { AA += (v2f){(V).x, (V).y}; BB += (v2f){(V).z, (V).w}; } while (0)

// ---- gather (single matrix): chunks of 8 + 2-col tail. Entry words are
// wave-uniform -> readfirstlane pins them to SGPRs so unpack/shift/base-add
// run on the scalar pipe and loads take saddr form (vaddr = lane16 only). ----
__device__ __forceinline__ void gather(v2f& A, v2f& B, const float* __restrict__ Wt,
                                       const u16* __restrict__ list, u32 np, u32 lane16) {
    const char* __restrict__ base = (const char*)Wt;
    u32 c = 0;
    for (; c + 8 <= np; c += 8) {
        uint4 d = *(const uint4*)(list + c);
        u32 w0 = rfl(d.x), w1 = rfl(d.y), w2 = rfl(d.z), w3 = rfl(d.w);
        const float4 v0 = *(const float4*)(base + ((w0 & 0xffffu) << 10) + lane16);
        const float4 v1 = *(const float4*)(base + ((w0 >> 16)     << 10) + lane16);
        const float4 v2 = *(const float4*)(base + ((w1 & 0xffffu) << 10) + lane16);
        const float4 v3 = *(const float4*)(base + ((w1 >> 16)     << 10) + lane16);
        const float4 v4 = *(const float4*)(base + ((w2 & 0xffffu) << 10) + lane16);
        const float4 v5 = *(const float4*)(base + ((w2 >> 16)     << 10) + lane16);
        const float4 v6 = *(const float4*)(base + ((w3 & 0xffffu) << 10) + lane16);
        const float4 v7 = *(const float4*)(base + ((w3 >> 16)     << 10) + lane16);
        GADD(A, B, v0); GADD(A, B, v1); GADD(A, B, v2); GADD(A, B, v3);
        GADD(A, B, v4); GADD(A, B, v5); GADD(A, B, v6); GADD(A, B, v7);
    }
    for (; c < np; c += 2) {                      // 2-col units (4-B aligned)
        u32 d = rfl(*(const u32*)(list + c));
        const float4 v0 = *(const float4*)(base + ((d & 0xffffu) << 10) + lane16);
        const float4 v1 = *(const float4*)(base + ((d >> 16)     << 10) + lane16);
        GADD(A, B, v0); GADD(A, B, v1);
    }
}

// ---- dual gather over the z1 segment: same cols on W2T and W3T in one pass;
// scalar-pinned offsets shared by both matrices. ----
__device__ __forceinline__ void gather_dual(v2f& A2, v2f& B2, v2f& A3, v2f& B3,
        const float* __restrict__ W2t, const float* __restrict__ W3t,
        const u16* __restrict__ list, u32 np, u32 lane16) {
    const char* __restrict__ p2 = (const char*)W2t;
    const char* __restrict__ p3 = (const char*)W3t;
    u32 c = 0;
    for (; c + 4 <= np; c += 4) {
        uint2 d = *(const uint2*)(list + c);
        u32 w0 = rfl(d.x), w1 = rfl(d.y);
        u32 o0 = (w0 & 0xffffu) << 10, o1 = (w0 >> 16) << 10;
        u32 o2 = (w1 & 0xffffu) << 10, o3 = (w1 >> 16) << 10;
        const float4 a0 = *(const float4*)(p2 + o0 + lane16);
        const float4 a1 = *(const float4*)(p2 + o1 + lane16);
        const float4 a2 = *(const float4*)(p2 + o2 + lane16);
        const float4 a3 = *(const float4*)(p2 + o3 + lane16);
        const float4 c0 = *(const float4*)(p3 + o0 + lane16);
        const float4 c1 = *(const float4*)(p3 + o1 + lane16);
        const float4 c2 = *(const float4*)(p3 + o2 + lane16);
        const float4 c3 = *(const float4*)(p3 + o3 + lane16);
        GADD(A2, B2, a0); GADD(A2, B2, a1); GADD(A2, B2, a2); GADD(A2, B2, a3);
        GADD(A3, B3, c0); GADD(A3, B3, c1); GADD(A3, B3, c2); GADD(A3, B3, c3);
    }
    for (; c < np; c += 2) {
        u32 d = rfl(*(const u32*)(list + c));
        u32 o0 = (d & 0xffffu) << 10, o1 = (d >> 16) << 10;
        const float4 a0 = *(const float4*)(p2 + o0 + lane16);
        const float4 a1 = *(const float4*)(p2 + o1 + lane16);
        const float4 c0 = *(const float4*)(p3 + o0 + lane16);
        const float4 c1 = *(const float4*)(p3 + o1 + lane16);
        GADD(A2, B2, a0); GADD(A2, B2, a1);
        GADD(A3, B3, c0); GADD(A3, B3, c1);
    }
}

// TWO waves = ONE block = ONE batch row (grid 4096 -> up to 32 waves/CU).
// Wave w owns: encoder features [w*512, w*512+512) (8/lane) and, per lane, the
// 2 neurons 4*lane + 2w + {0,1} (= accumulator components {2w, 2w+1}).
// Each wave builds PRIVATE spike lists from its own neurons and gathers them at
// FULL row width (float4/lane) -> total loads/adds per CU unchanged vs 1-wave
// version; per-phase, waves exchange the other-owner half of their partial
// accumulator through LDS (8 B/lane + 1 barrier). Nothing is computed twice.
// launch_bounds min-arg 4 (NOT 8): the (128,8) variant made the allocator pin
// VGPR=32 and spill into the hot loop (rocprof: 320MB/12.5MB scratch writes,
// rounds 1-2). 128-reg budget lets it land at its natural ~60, zero spill.
__global__ __launch_bounds__(128, 4) void snn_k(const void* __restrict__ xin,
                                                const float* __restrict__ ws,
                                                void* __restrict__ out) {
    const u32 tid  = threadIdx.x;
    const u32 w    = rfl(tid >> 6);      // wave id 0/1 -> SGPR
    const u32 lane = tid & 63;
    const int row  = blockIdx.x;
    const u32 lane16 = lane * 16;
    const u32 k0 = w << 1;               // owned components {k0, k0+1} (SGPR)
    const u32 isbf = detect_bf16(xin, lane);

    const float* __restrict__ W1T = ws + OFF_W1T;
    const float* __restrict__ W2T = ws + OFF_W2T;
    const float* __restrict__ W3T = ws + OFF_W3T;
    const float* __restrict__ WLI = ws + OFF_WLI;

    __shared__ u32 sched[6 * 128];               // 3 KB: 4 steps per u32, 8 bits/step
    __shared__ __align__(16) u16 lE[2][512];     // 2 KB: per-wave encoder lists
    __shared__ __align__(16) u16 lL[2][264];     // 1 KB: per-wave z lists (z1 + z2 seg)
    __shared__ v2f exb[3][2][64];                // 3 KB: per-phase partial-acc exchange
    __shared__ float redsm[2][NCLS];

    // ---- encoder precompute: 24-step spike schedule for my 8 features ----
    {
        float xv[8];
        if (isbf) {
            const u16* xb = (const u16*)xin + (size_t)row * FEAT;
            uint4 A = *(const uint4*)(xb + tid * 8);
            u32 wd[4] = {A.x, A.y, A.z, A.w};
            #pragma unroll
            for (int i = 0; i < 4; i++) {
                xv[2*i]   = __uint_as_float(wd[i] << 16);
                xv[2*i+1] = __uint_as_float(wd[i] & 0xffff0000u);
            }
        } else {
            const float* xf = (const float*)xin + (size_t)row * FEAT;
            float4 A = ((const float4*)xf)[tid * 2];
            float4 B = ((const float4*)xf)[tid * 2 + 1];
            xv[0]=A.x; xv[1]=A.y; xv[2]=A.z; xv[3]=A.w;
            xv[4]=B.x; xv[5]=B.y; xv[6]=B.z; xv[7]=B.w;
        }
        u32 smreg[6];
        #pragma unroll
        for (int i = 0; i < 6; i++) smreg[i] = 0;
        #pragma unroll
        for (int j = 0; j < 8; j++) {
            float v = 0.f;
            #pragma unroll
            for (int t = 0; t < TSTEPS; t++) {
                v = v + 0.1f * (xv[j] - v);
                bool z = v > 1.0f;
                v = z ? 0.0f : v;
                if (z) smreg[t >> 2] |= 1u << (((t & 3) << 3) + j);
            }
        }
        #pragma unroll
        for (int i = 0; i < 6; i++) sched[i * 128 + tid] = smreg[i];
        // threads read back only their own words -> no barrier needed
    }

    float v1[2], i1[2], v2_[2], i2[2], v3[2], i3[2], g[2];
    #pragma unroll
    for (int k = 0; k < 2; k++) {
        v1[k]=0.f; i1[k]=0.f; v2_[k]=0.f; i2[k]=0.f; v3[k]=0.f; i3[k]=0.f; g[k]=0.f;
    }
    const u32 lane4 = lane * 4;
    // own-component biases only: float2 each, added once post-exchange (6 VGPRs)
    const v2f b1o = *(const v2f*)(ws + OFF_B1 + lane4 + k0);
    const v2f b2o = *(const v2f*)(ws + OFF_B2 + lane4 + k0);
    const v2f b3o = *(const v2f*)(ws + OFF_B3 + lane4 + k0);
    const u32 colbaseE = w << 9;                 // encoder col base: 0 / 512 (SGPR)

    u32 curw = 0;
    #pragma unroll 1
    for (int t = 0; t < TSTEPS; t++) {
        if ((t & 3) == 0) curw = sched[(t >> 2) * 128 + tid];
        const u32 lmE = (curw >> ((t & 3) << 3)) & 0xffu;

        // ---- layer 1: gather my encoder-half cols at full width ----
        v2f accA = {0.f, 0.f}, accB = {0.f, 0.f};
        if (__ballot(lmE != 0u)) {
            u32 npE = build_listE8(lE[w], lmE, lane, colbaseE);
            gather(accA, accB, W1T, lE[w], npE, lane16);
        }
        exb[0][w][lane] = w ? accA : accB;        // ship other-owner half
        __syncthreads();
        v2f own1 = (w ? accB : accA) + exb[0][w ^ 1][lane] + b1o;

        float a1[2] = {own1.x, own1.y};
        float o1v[2]; u32 lm1 = 0;
        #pragma unroll
        for (int kk = 0; kk < 2; kk++) {
            float vd = v1[kk] + 0.1f * (i1[kk] - v1[kk]);
            i1[kk] = i1[kk] * 0.8f;
            bool z = vd > 0.23f;
            v1[kk] = z ? 0.0f : vd;
            i1[kk] = i1[kk] + a1[kk];
            o1v[kk] = z ? 1.0f : 0.0f;
            lm1 |= (z ? 1u : 0u) << kk;
        }

        // ---- layers 2+3a: my z1 cols, dual gather on W2T & W3T ----
        v2f acc2A = {0.f, 0.f}, acc2B = {0.f, 0.f};
        v2f acc3A = {0.f, 0.f}, acc3B = {0.f, 0.f};
        u32 np1 = 0;
        if (__ballot(lm1 != 0u)) {
            np1 = build_listZ2(lL[w], lm1, 0u, lane, k0);
            gather_dual(acc2A, acc2B, acc3A, acc3B, W2T, W3T, lL[w], np1, lane16);
        }
        exb[1][w][lane] = w ? acc2A : acc2B;
        __syncthreads();
        v2f own2 = (w ? acc2B : acc2A) + exb[1][w ^ 1][lane] + b2o;

        float a2[2] = {own2.x, own2.y};
        float o2v[2]; u32 lm2 = 0;
        #pragma unroll
        for (int kk = 0; kk < 2; kk++) {
            float vd = v2_[kk] + 0.1f * (i2[kk] - v2_[kk]);
            i2[kk] = i2[kk] * 0.8f;
            bool z = vd > 0.23f;
            v2_[kk] = z ? 0.0f : vd;
            i2[kk] = i2[kk] + a2[kk];
            o2v[kk] = (z ? 1.0f : 0.0f) + o1v[kk];
            lm2 |= (z ? 1u : 0u) << kk;
        }

        // ---- layer 3b: append my z2 cols at padded np1, gather on W3T.
        //      o2 = z1 + z2 via duplicate cols (exact). ----
        if (__ballot(lm2 != 0u)) {
            u32 np2 = build_listZ2(lL[w], lm2, np1, lane, k0);
            gather(acc3A, acc3B, W3T, lL[w] + np1, np2 - np1, lane16);
        }
        exb[2][w][lane] = w ? acc3A : acc3B;
        __syncthreads();
        v2f own3 = (w ? acc3B : acc3A) + exb[2][w ^ 1][lane] + b3o;

        float a3[2] = {own3.x, own3.y};
        const float cf = COEF.c[t];
        #pragma unroll
        for (int kk = 0; kk < 2; kk++) {
            float vd = v3[kk] + 0.1f * (i3[kk] - v3[kk]);
            i3[kk] = i3[kk] * 0.8f;
            bool z = vd > 0.23f;
            v3[kk] = z ? 0.0f : vd;
            i3[kk] = i3[kk] + a3[kk];
            float o3 = (z ? 1.0f : 0.0f) + o2v[kk];
            g[kk] += cf * o3;
        }
    }

    // ---- epilogue: vo_24[c] = sum_h g[h]*Wli[c][h]; cross-wave via LDS ----
    float s[NCLS];
    #pragma unroll
    for (int c = 0; c < NCLS; c++) {
        const float2 wv = *(const float2*)(WLI + c * HID + lane4 + k0);
        float p = g[0] * wv.x + g[1] * wv.y;
        #pragma unroll
        for (int d = 32; d > 0; d >>= 1) p += __shfl_xor(p, d, 64);
        s[c] = p;
    }
    if (lane == 0) {
        #pragma unroll
        for (int c = 0; c < NCLS; c++) redsm[w][c] = s[c];
    }
    __syncthreads();
    if (tid == 0) {
        if (isbf) {
            __hip_bfloat16* o = (__hip_bfloat16*)out + (size_t)row * NCLS;
            #pragma unroll
            for (int c = 0; c < NCLS; c++) o[c] = __float2bfloat16(redsm[0][c] + redsm[1][c]);
        } else {
            float* o = (float*)out + (size_t)row * NCLS;
            #pragma unroll
            for (int c = 0; c < NCLS; c++) o[c] = redsm[0][c] + redsm[1][c];
        }
    }
}

extern "C" void kernel_launch(void* const* d_in, const int* in_sizes, int n_in,
                              void* d_out, int out_size, void* d_ws, size_t ws_size,
                              hipStream_t stream) {
    const void* x   = d_in[0];
    const void* W1  = d_in[1];
    const void* b1  = d_in[2];
    const void* W2  = d_in[3];
    const void* b2  = d_in[4];
    const void* W3  = d_in[5];
    const void* b3  = d_in[6];
    const void* Wli = d_in[7];
    float* ws = (float*)d_ws;
    const int batch = in_sizes[0] / FEAT;   // 4096

    prep_k<<<385, 256, 0, stream>>>(x, W1, W2, W3, Wli, b1, b2, b3, ws);
    snn_k<<<batch, 128, 0, stream>>>(x, ws, d_out);
}

// Round 4
// 144.366 us; speedup vs baseline: 1.1460x; 1.1460x over previous
//
#include <hip/hip_runtime.h>
#include <hip/hip_bf16.h>

#define FEAT   1024
#define HID    256
#define TSTEPS 24
#define NCLS   10

typedef unsigned int u32;
typedef unsigned long long u64;
typedef unsigned short u16;
typedef float v2f __attribute__((ext_vector_type(2)));

// ---- workspace layout (float offsets). W1T/W2T/W3T carry one extra ZERO row
// (col 1024 / 256) targeted by list padding -> gathers are pure adds.
constexpr int OFF_W1T  = 0;                     // [1025][256] fp32 (W1^T + zero row)
constexpr int OFF_W2T  = OFF_W1T + 1025*HID;    // [257][256]
constexpr int OFF_W3T  = OFF_W2T + 257*HID;     // [257][256]
constexpr int OFF_WLI  = OFF_W3T + 257*HID;     // [10][256] plain copy
constexpr int OFF_B1   = OFF_WLI + NCLS*HID;
constexpr int OFF_B2   = OFF_B1 + HID;
constexpr int OFF_B3   = OFF_B2 + HID;

// ---- LI readout linearized: vo_24 = sum_t coef[t] * (o3_t @ Wli^T).
struct CoefT { float c[TSTEPS]; };
constexpr CoefT make_coef() {
    CoefT r{};
    double c = 0.0, p9 = 1.0;
    r.c[TSTEPS-1] = 0.0f;
    for (int u = TSTEPS-1; u > 0; u--) {
        c = 0.8 * c + 0.1 * p9;
        p9 *= 0.9;
        r.c[u-1] = (float)c;
    }
    return r;
}
__device__ constexpr CoefT COEF = make_coef();

__device__ __forceinline__ u32 rfl(u32 v) {
    return (u32)__builtin_amdgcn_readfirstlane((int)v);   // pin wave-uniform -> SGPR
}

// ---- in-wave dtype detect: fp32 viewed as bf16 -> exponent garbage at even idx.
__device__ __forceinline__ u32 detect_bf16(const void* __restrict__ x, u32 lane) {
    float v = __bfloat162float(((const __hip_bfloat16*)x)[lane]);
    u64 bad = __ballot(!(fabsf(v) < 100.0f));
    return bad == 0ull ? 1u : 0u;
}

__device__ __forceinline__ float rd_any(const void* p, int idx, u32 isbf) {
    return isbf ? __bfloat162float(((const __hip_bfloat16*)p)[idx])
                : ((const float*)p)[idx];
}

__device__ __forceinline__ float4 rd4(const void* p, int i, u32 isbf) {
    if (isbf) {
        const u32* q = (const u32*)p;
        u32 a = q[i >> 1], b = q[(i >> 1) + 1];
        float4 r;
        r.x = __uint_as_float(a << 16); r.y = __uint_as_float(a & 0xffff0000u);
        r.z = __uint_as_float(b << 16); r.w = __uint_as_float(b & 0xffff0000u);
        return r;
    }
    return ((const float4*)p)[i >> 2];
}

// ---- prep: 32x32 LDS-tiled transpose, coalesced float4 both sides, 385 blocks.
__global__ __launch_bounds__(256) void prep_k(const void* __restrict__ x,
        const void* W1, const void* W2, const void* W3, const void* Wli,
        const void* b1, const void* b2, const void* b3, float* __restrict__ ws) {
    const u32 isbf = detect_bf16(x, threadIdx.x & 63);
    const u32 t = threadIdx.x;
    int b = blockIdx.x;

    if (b == 384) {   // tail: Wli + biases + zero rows (all coalesced)
        for (u32 e = t; e < NCLS*HID; e += 256) ws[OFF_WLI + e] = rd_any(Wli, e, isbf);
        ws[OFF_B1 + t] = rd_any(b1, t, isbf);
        ws[OFF_B2 + t] = rd_any(b2, t, isbf);
        ws[OFF_B3 + t] = rd_any(b3, t, isbf);
        ws[OFF_W1T + 1024*HID + t] = 0.f;
        ws[OFF_W2T + 256*HID + t] = 0.f;
        ws[OFF_W3T + 256*HID + t] = 0.f;
        return;
    }

    const void* src; float* dst; int srcW, h0, f0;
    if (b < 256)      { src = W1; dst = ws + OFF_W1T; srcW = FEAT; h0 = (b >> 5) * 32; f0 = (b & 31) * 32; }
    else if (b < 320) { int tb = b - 256; src = W2; dst = ws + OFF_W2T; srcW = HID; h0 = (tb >> 3) * 32; f0 = (tb & 7) * 32; }
    else              { int tb = b - 320; src = W3; dst = ws + OFF_W3T; srcW = HID; h0 = (tb >> 3) * 32; f0 = (tb & 7) * 32; }

    __shared__ float sm[32 * 36];
    {
        u32 r = t >> 3, c4 = (t & 7) * 4;
        float4 w = rd4(src, (h0 + r) * srcW + f0 + c4, isbf);
        *(float4*)&sm[r * 36 + c4] = w;
    }
    __syncthreads();
    {
        u32 f = t >> 3, h4 = (t & 7) * 4;
        float4 o;
        o.x = sm[(h4 + 0) * 36 + f];
        o.y = sm[(h4 + 1) * 36 + f];
        o.z = sm[(h4 + 2) * 36 + f];
        o.w = sm[(h4 + 3) * 36 + f];
        *(float4*)&dst[(size_t)(f0 + f) * HID + h0 + h4] = o;
    }
}

__device__ __forceinline__ u32 mbcnt64(u64 m) {
    return __builtin_amdgcn_mbcnt_hi((u32)(m >> 32),
           __builtin_amdgcn_mbcnt_lo((u32)m, 0u));
}

// ---- list builders: u16 col-index entries; branch-free prefix via weighted
// bit-plane ballots; pad to EVEN count with the zero-row col. ----

// encoder: 16 features/lane, col = 16*lane + j; zero col = 1024. returns padded np.
// max written index = 1023, max np = 1024 -> 1024-entry buffer suffices.
__device__ __forceinline__ u32 build_listE(u16* list, u32 lm, u32 lane) {
    u32 cnt = (u32)__builtin_popcount(lm);
    u32 pos = 0, n = 0;
    #pragma unroll
    for (int b = 0; b < 5; b++) {
        u64 B = __ballot(((cnt >> b) & 1u) != 0);
        pos += mbcnt64(B) << b;
        n += ((u32)__builtin_popcountll(B)) << b;
    }
    while (lm) {
        u32 j = (u32)__builtin_ctz(lm); lm &= lm - 1;
        list[pos++] = (u16)((lane << 4) + j);
    }
    u32 np = (n + 1u) & ~1u;
    if (lane == 0 && np != n) list[n] = (u16)1024;
    return np;
}

// z layers: 4 neurons/lane, col = 4*lane + j; zero col = 256; append at start
// (start must be even). returns padded end (even).
__device__ __forceinline__ u32 build_listZ(u16* list, u32 lm, u32 start, u32 lane) {
    u32 cnt = (u32)__builtin_popcount(lm);
    u64 B0 = __ballot((cnt & 1u) != 0);
    u64 B1 = __ballot((cnt & 2u) != 0);
    u64 B2 = __ballot((cnt & 4u) != 0);
    u32 pos = start + mbcnt64(B0) + 2u*mbcnt64(B1) + 4u*mbcnt64(B2);
    u32 n = start + (u32)__builtin_popcountll(B0) + 2u*(u32)__builtin_popcountll(B1)
          + 4u*(u32)__builtin_popcountll(B2);
    while (lm) {
        u32 j = (u32)__builtin_ctz(lm); lm &= lm - 1;
        list[pos++] = (u16)((lane << 2) + j);
    }
    u32 np = (n + 1u) & ~1u;
    if (lane == 0 && np != n) list[n] = (u16)256;
    return np;
}

#define GADD(AA, BB, V) do { AA += (v2f){(V).x, (V).y}; BB += (v2f){(V).z, (V).w}; } while (0)

// ---- gather (single matrix): chunks of 8 + 2-col tail. Entry words are
// wave-uniform -> readfirstlane pins them to SGPRs so unpack/shift/base-add
// run on the scalar pipe and loads take saddr form (vaddr = lane16 only). ----
__device__ __forceinline__ void gather(v2f& A, v2f& B, const float* __restrict__ Wt,
                                       const u16* __restrict__ list, u32 np, u32 lane16) {
    const char* __restrict__ base = (const char*)Wt;
    u32 c = 0;
    for (; c + 8 <= np; c += 8) {
        uint4 d = *(const uint4*)(list + c);
        u32 w0 = rfl(d.x), w1 = rfl(d.y), w2 = rfl(d.z), w3 = rfl(d.w);
        const float4 v0 = *(const float4*)(base + ((w0 & 0xffffu) << 10) + lane16);
        const float4 v1 = *(const float4*)(base + ((w0 >> 16)     << 10) + lane16);
        const float4 v2 = *(const float4*)(base + ((w1 & 0xffffu) << 10) + lane16);
        const float4 v3 = *(const float4*)(base + ((w1 >> 16)     << 10) + lane16);
        const float4 v4 = *(const float4*)(base + ((w2 & 0xffffu) << 10) + lane16);
        const float4 v5 = *(const float4*)(base + ((w2 >> 16)     << 10) + lane16);
        const float4 v6 = *(const float4*)(base + ((w3 & 0xffffu) << 10) + lane16);
        const float4 v7 = *(const float4*)(base + ((w3 >> 16)     << 10) + lane16);
        GADD(A, B, v0); GADD(A, B, v1); GADD(A, B, v2); GADD(A, B, v3);
        GADD(A, B, v4); GADD(A, B, v5); GADD(A, B, v6); GADD(A, B, v7);
    }
    for (; c < np; c += 2) {                      // 2-col units (4-B aligned)
        u32 d = rfl(*(const u32*)(list + c));
        const float4 v0 = *(const float4*)(base + ((d & 0xffffu) << 10) + lane16);
        const float4 v1 = *(const float4*)(base + ((d >> 16)     << 10) + lane16);
        GADD(A, B, v0); GADD(A, B, v1);
    }
}

// ---- dual gather over the z1 segment: same cols on W2T and W3T in one pass;
// scalar-pinned offsets shared by both matrices. ----
__device__ __forceinline__ void gather_dual(v2f& A2, v2f& B2, v2f& A3, v2f& B3,
        const float* __restrict__ W2t, const float* __restrict__ W3t,
        const u16* __restrict__ list, u32 np, u32 lane16) {
    const char* __restrict__ p2 = (const char*)W2t;
    const char* __restrict__ p3 = (const char*)W3t;
    u32 c = 0;
    for (; c + 4 <= np; c += 4) {
        uint2 d = *(const uint2*)(list + c);
        u32 w0 = rfl(d.x), w1 = rfl(d.y);
        u32 o0 = (w0 & 0xffffu) << 10, o1 = (w0 >> 16) << 10;
        u32 o2 = (w1 & 0xffffu) << 10, o3 = (w1 >> 16) << 10;
        const float4 a0 = *(const float4*)(p2 + o0 + lane16);
        const float4 a1 = *(const float4*)(p2 + o1 + lane16);
        const float4 a2 = *(const float4*)(p2 + o2 + lane16);
        const float4 a3 = *(const float4*)(p2 + o3 + lane16);
        const float4 c0 = *(const float4*)(p3 + o0 + lane16);
        const float4 c1 = *(const float4*)(p3 + o1 + lane16);
        const float4 c2 = *(const float4*)(p3 + o2 + lane16);
        const float4 c3 = *(const float4*)(p3 + o3 + lane16);
        GADD(A2, B2, a0); GADD(A2, B2, a1); GADD(A2, B2, a2); GADD(A2, B2, a3);
        GADD(A3, B3, c0); GADD(A3, B3, c1); GADD(A3, B3, c2); GADD(A3, B3, c3);
    }
    for (; c < np; c += 2) {
        u32 d = rfl(*(const u32*)(list + c));
        u32 o0 = (d & 0xffffu) << 10, o1 = (d >> 16) << 10;
        const float4 a0 = *(const float4*)(p2 + o0 + lane16);
        const float4 a1 = *(const float4*)(p2 + o1 + lane16);
        const float4 c0 = *(const float4*)(p3 + o0 + lane16);
        const float4 c1 = *(const float4*)(p3 + o1 + lane16);
        GADD(A2, B2, a0); GADD(A2, B2, a1);
        GADD(A3, B3, c0); GADD(A3, B3, c1);
    }
}

// ONE wave = ONE batch row; TWO INDEPENDENT waves per 128-thread block
// (rows 2*blockIdx + {0,1}). No barriers, no cross-wave traffic — packing two
// waves per workgroup doubles the resident-wave limit that capped the 64-thread
// version at 16 waves/CU (round-0 occupancy 33%). Per-wave LDS trimmed to
// 5120 B (sched 3 KB + a UNIONED list buffer: lE is dead after the layer-1
// gather, lL is dead before the next step's lE build, and lE's true bound is
// 1024 entries) -> 10240 B/block exactly -> 16 blocks/CU -> up to 32 waves/CU.
// launch_bounds min-arg 4: the (x,8) form made the allocator pin VGPR=32 and
// spill into the hot loop (rounds 1-2); body naturally needs ~60 VGPRs.
__global__ __launch_bounds__(128, 4) void snn_k(const void* __restrict__ xin,
                                                const float* __restrict__ ws,
                                                void* __restrict__ out,
                                                int batch) {
    const u32 tid  = threadIdx.x;
    const u32 w    = tid >> 6;                   // independent wave 0/1
    const u32 lane = tid & 63;
    const int row  = blockIdx.x * 2 + (int)w;
    if (row >= batch) return;
    const u32 lane16 = lane * 16;
    const u32 isbf = detect_bf16(xin, lane);

    const float* __restrict__ W1T = ws + OFF_W1T;
    const float* __restrict__ W2T = ws + OFF_W2T;
    const float* __restrict__ W3T = ws + OFF_W3T;
    const float* __restrict__ WLI = ws + OFF_WLI;

    __shared__ u32 sched[2][12 * 64];            // 6 KB: per-wave spike schedule
    __shared__ __align__(16) u16 lst[2][1024];   // 4 KB: per-wave lE/lL UNION
    u16* const lE = lst[w];
    u16* const lL = lst[w];                      // disjoint lifetimes within a step

    // ---- encoder precompute: 24-step spike schedule for my 16 features ----
    {
        float xv[16];
        if (isbf) {
            const uint4* xp = (const uint4*)((const u16*)xin + (size_t)row*FEAT + lane*16);
            uint4 A = xp[0], B = xp[1];
            u32 wd[8] = {A.x, A.y, A.z, A.w, B.x, B.y, B.z, B.w};
            #pragma unroll
            for (int i = 0; i < 8; i++) {
                xv[2*i]   = __uint_as_float(wd[i] << 16);
                xv[2*i+1] = __uint_as_float(wd[i] & 0xffff0000u);
            }
        } else {
            const float4* xp = (const float4*)((const float*)xin + (size_t)row*FEAT + lane*16);
            float4 A = xp[0], B = xp[1], C = xp[2], D = xp[3];
            float tmp[16] = {A.x,A.y,A.z,A.w,B.x,B.y,B.z,B.w,C.x,C.y,C.z,C.w,D.x,D.y,D.z,D.w};
            #pragma unroll
            for (int i = 0; i < 16; i++) xv[i] = tmp[i];
        }
        u32 smreg[12];
        #pragma unroll
        for (int i = 0; i < 12; i++) smreg[i] = 0;
        #pragma unroll
        for (int j = 0; j < 16; j++) {
            float v = 0.f;
            #pragma unroll
            for (int t = 0; t < TSTEPS; t++) {
                v = v + 0.1f * (xv[j] - v);
                bool z = v > 1.0f;
                v = z ? 0.0f : v;
                if (z) smreg[t >> 1] |= 1u << (((t & 1) << 4) + j);
            }
        }
        #pragma unroll
        for (int i = 0; i < 12; i++) sched[w][i * 64 + lane] = smreg[i];
        // lanes read back only their own words -> no barrier needed
    }

    float v1[4], i1[4], v2[4], i2[4], v3[4], i3[4], g[4];
    #pragma unroll
    for (int k = 0; k < 4; k++) {
        v1[k]=0.f; i1[k]=0.f; v2[k]=0.f; i2[k]=0.f; v3[k]=0.f; i3[k]=0.f; g[k]=0.f;
    }
    const u32 lane4 = lane * 4;
    const float4 b1v = *(const float4*)(ws + OFF_B1 + lane4);
    const float4 b2v = *(const float4*)(ws + OFF_B2 + lane4);
    const float4 b3v = *(const float4*)(ws + OFF_B3 + lane4);

    u32 pairreg = 0;
    for (int t = 0; t < TSTEPS; t++) {
        if ((t & 1) == 0) pairreg = sched[w][(t >> 1) * 64 + lane];
        const u32 lmE = (t & 1) ? (pairreg >> 16) : (pairreg & 0xffffu);

        // ---- layer 1 (skip build+gather if no encoder spikes this step) ----
        v2f accA = {b1v.x, b1v.y}, accB = {b1v.z, b1v.w};
        if (__ballot(lmE != 0u)) {
            u32 npE = build_listE(lE, lmE, lane);
            gather(accA, accB, W1T, lE, npE, lane16);
        }
        float a1[4] = {accA.x, accA.y, accB.x, accB.y};

        float o1v[4]; u32 lm1 = 0;
        #pragma unroll
        for (int kk = 0; kk < 4; kk++) {
            float vd = v1[kk] + 0.1f * (i1[kk] - v1[kk]);
            i1[kk] = i1[kk] * 0.8f;
            bool z = vd > 0.23f;
            v1[kk] = z ? 0.0f : vd;
            i1[kk] = i1[kk] + a1[kk];
            o1v[kk] = z ? 1.0f : 0.0f;
            lm1 |= (z ? 1u : 0u) << kk;
        }

        // ---- layers 2+3a: z1 cols, dual gather on W2T & W3T ----
        v2f acc2A = {b2v.x, b2v.y}, acc2B = {b2v.z, b2v.w};
        v2f acc3A = {b3v.x, b3v.y}, acc3B = {b3v.z, b3v.w};
        u32 np1 = 0;
        if (__ballot(lm1 != 0u)) {
            np1 = build_listZ(lL, lm1, 0u, lane);
            gather_dual(acc2A, acc2B, acc3A, acc3B, W2T, W3T, lL, np1, lane16);
        }
        float a2[4] = {acc2A.x, acc2A.y, acc2B.x, acc2B.y};

        float o2v[4]; u32 lm2 = 0;
        #pragma unroll
        for (int kk = 0; kk < 4; kk++) {
            float vd = v2[kk] + 0.1f * (i2[kk] - v2[kk]);
            i2[kk] = i2[kk] * 0.8f;
            bool z = vd > 0.23f;
            v2[kk] = z ? 0.0f : vd;
            i2[kk] = i2[kk] + a2[kk];
            o2v[kk] = (z ? 1.0f : 0.0f) + o1v[kk];
            lm2 |= (z ? 1u : 0u) << kk;
        }

        // ---- layer 3b: append z2 at padded np1, gather [np1, np2) on W3T.
        //      o2 = z1 + z2 via duplicate cols (exact). ----
        if (__ballot(lm2 != 0u)) {
            u32 np2 = build_listZ(lL, lm2, np1, lane);
            gather(acc3A, acc3B, W3T, lL + np1, np2 - np1, lane16);
        }
        float a3[4] = {acc3A.x, acc3A.y, acc3B.x, acc3B.y};

        const float cf = COEF.c[t];
        #pragma unroll
        for (int kk = 0; kk < 4; kk++) {
            float vd = v3[kk] + 0.1f * (i3[kk] - v3[kk]);
            i3[kk] = i3[kk] * 0.8f;
            bool z = vd > 0.23f;
            v3[kk] = z ? 0.0f : vd;
            i3[kk] = i3[kk] + a3[kk];
            float o3 = (z ? 1.0f : 0.0f) + o2v[kk];
            g[kk] += cf * o3;
        }
    }

    // ---- epilogue: vo_24[c] = sum_h g[h]*Wli[c][h] ----
    float s[NCLS];
    #pragma unroll
    for (int c = 0; c < NCLS; c++) {
        const float4 wv = *(const float4*)(WLI + c*HID + lane4);
        float p = g[0]*wv.x + g[1]*wv.y + g[2]*wv.z + g[3]*wv.w;
        #pragma unroll
        for (int d = 32; d > 0; d >>= 1) p += __shfl_xor(p, d, 64);
        s[c] = p;
    }
    if (lane == 0) {
        if (isbf) {
            __hip_bfloat16* o = (__hip_bfloat16*)out + (size_t)row*NCLS;
            #pragma unroll
            for (int c = 0; c < NCLS; c++) o[c] = __float2bfloat16(s[c]);
        } else {
            float* o = (float*)out + (size_t)row*NCLS;
            #pragma unroll
            for (int c = 0; c < NCLS; c++) o[c] = s[c];
        }
    }
}

extern "C" void kernel_launch(void* const* d_in, const int* in_sizes, int n_in,
                              void* d_out, int out_size, void* d_ws, size_t ws_size,
                              hipStream_t stream) {
    const void* x   = d_in[0];
    const void* W1  = d_in[1];
    const void* b1  = d_in[2];
    const void* W2  = d_in[3];
    const void* b2  = d_in[4];
    const void* W3  = d_in[5];
    const void* b3  = d_in[6];
    const void* Wli = d_in[7];
    float* ws = (float*)d_ws;
    const int batch = in_sizes[0] / FEAT;   // 4096

    prep_k<<<385, 256, 0, stream>>>(x, W1, W2, W3, Wli, b1, b2, b3, ws);
    snn_k<<<(batch + 1) / 2, 128, 0, stream>>>(x, ws, d_out, batch);
}